// Round 4
// baseline (158.721 us; speedup 1.0000x reference)
//
#include <hip/hip_runtime.h>
#include <hip/hip_bf16.h>

// out[m,o] = sum_k x[m,k] * (W[o,k]*scale) + bias[o]
// M=1024, K=4096, N=11008.
// Pre-pass: W(int32)->bf16 + X(f32)->bf16 into d_ws (one kernel, BW-bound).
// GEMM: 256x256 tile, BK=64, 512 thr (8 waves 2Mx4N, per-wave 128x64),
//       m201-style 4-phase/K-tile schedule: counted vmcnt(4), per-phase
//       barriers, lgkmcnt(0)+sched_barrier before MFMA cluster, setprio,
//       T2 swizzle (linear gload_lds dest + pre-swizzled global source +
//       swizzled ds_read). Grid 43x4=172 (M=1024 caps it); win comes from
//       per-CU rate, not block count.

#define M_TOT 1024
#define N_TOT 11008
#define K_TOT 4096
#define BM 256
#define BN 256
#define BK 64
#define NT (K_TOT / BK)  // 64 K-steps
#define ABYTES (BM * BK * 2)          // 32 KB
#define BUFB   ((BM + BN) * BK * 2)   // 64 KB per buffer

typedef __attribute__((ext_vector_type(8))) short short8;   // 8 bf16
typedef __attribute__((ext_vector_type(4))) float f32x4;

__device__ __forceinline__ unsigned short f2bf(float f) {
    __hip_bfloat16 h = __float2bfloat16(f);  // RNE
    return __builtin_bit_cast(unsigned short, h);
}

__device__ __forceinline__ void gload16(const void* g, void* l) {
    __builtin_amdgcn_global_load_lds(
        (const __attribute__((address_space(1))) unsigned int*)g,
        (__attribute__((address_space(3))) unsigned int*)l,
        16, 0, 0);
}

// ---------------- pre-pass: W int32->bf16 (exact) and X f32->bf16 ----------------
__global__ void conv_kernel(const int* __restrict__ W, const float* __restrict__ X,
                            __hip_bfloat16* __restrict__ Wb, __hip_bfloat16* __restrict__ Xb,
                            int wn8, int xn8) {
    int idx = blockIdx.x * blockDim.x + threadIdx.x;
    int stride = gridDim.x * blockDim.x;
    int total = wn8 + xn8;
    for (int i = idx; i < total; i += stride) {
        short8 o;
        if (i < wn8) {
            const int4* p = (const int4*)W + (size_t)i * 2;
            int4 a = p[0], b = p[1];
            o[0] = (short)f2bf((float)a.x); o[1] = (short)f2bf((float)a.y);
            o[2] = (short)f2bf((float)a.z); o[3] = (short)f2bf((float)a.w);
            o[4] = (short)f2bf((float)b.x); o[5] = (short)f2bf((float)b.y);
            o[6] = (short)f2bf((float)b.z); o[7] = (short)f2bf((float)b.w);
            *(short8*)(Wb + (size_t)i * 8) = o;
        } else {
            int j = i - wn8;
            const f32x4* p = (const f32x4*)X + (size_t)j * 2;
            f32x4 a = p[0], b = p[1];
            o[0] = (short)f2bf(a[0]); o[1] = (short)f2bf(a[1]);
            o[2] = (short)f2bf(a[2]); o[3] = (short)f2bf(a[3]);
            o[4] = (short)f2bf(b[0]); o[5] = (short)f2bf(b[1]);
            o[6] = (short)f2bf(b[2]); o[7] = (short)f2bf(b[3]);
            *(short8*)(Xb + (size_t)j * 8) = o;
        }
    }
}

// ---------------- main GEMM: bf16 NT, 256^2, 4-phase counted-vmcnt ----------------
__global__ __launch_bounds__(512, 2)
void gemm_bf16_kernel(const __hip_bfloat16* __restrict__ Xb,   // [1024,4096]
                      const __hip_bfloat16* __restrict__ Wb,   // [11008,4096]
                      const float* __restrict__ scale,
                      const float* __restrict__ bias,
                      float* __restrict__ out) {               // [1024,11008]
    __shared__ __align__(16) unsigned char lds[2 * BUFB];      // 128 KB

    const int tid  = threadIdx.x;     // 0..511
    const int lane = tid & 63;
    const int wid  = tid >> 6;        // 0..7
    const int wr   = wid >> 2;        // 0..1  (128-row half)
    const int wc   = wid & 3;         // 0..3  (64-col strip)
    const int lr   = lane & 15;
    const int kb   = lane >> 4;       // 0..3

    const int brow = blockIdx.y * BM;
    const int bcol = blockIdx.x * BN;

    // staging: per wave 32 rows A + 32 rows B, 4 chunks of 8 rows each.
    // gload_lds dest linear; global source col pre-swizzled so LDS content
    // matches the read-side XOR: src col = ((l&7) ^ (l>>3)) * 8 elems.
    const int s_row  = wid * 32 + (lane >> 3);
    const int s_cole = (((lane & 7) ^ (lane >> 3)) * 8);

    const __hip_bfloat16* asrc0 = Xb + (size_t)(brow + s_row) * K_TOT + s_cole;
    const __hip_bfloat16* bsrc0 = Wb + (size_t)(bcol + s_row) * K_TOT + s_cole;
    const int lds_row0 = wid * 32;

    auto stageA = [&](int t, unsigned char* buf) {
        const size_t k0 = (size_t)t * BK;
#pragma unroll
        for (int i = 0; i < 4; ++i)
            gload16(asrc0 + k0 + (size_t)i * 8 * K_TOT, buf + (lds_row0 + i * 8) * 128);
    };
    auto stageB = [&](int t, unsigned char* buf) {
        const size_t k0 = (size_t)t * BK;
#pragma unroll
        for (int i = 0; i < 4; ++i)
            gload16(bsrc0 + k0 + (size_t)i * 8 * K_TOT, buf + ABYTES + (lds_row0 + i * 8) * 128);
    };

    f32x4 acc[8][4];
#pragma unroll
    for (int m = 0; m < 8; ++m)
#pragma unroll
        for (int n = 0; n < 4; ++n)
#pragma unroll
            for (int i = 0; i < 4; ++i) acc[m][n][i] = 0.0f;

    // prologue: stage tile 0 into buf0 (gated at t=0 phase 0 by vmcnt(4))
    stageA(0, lds);
    stageB(0, lds);

    for (int t = 0; t < NT; ++t) {
        const unsigned char* cur = lds + (size_t)(t & 1) * BUFB;
        unsigned char* nxt = lds + (size_t)((t + 1) & 1) * BUFB;
        const int tn = (t + 1 < NT) ? (t + 1) : 0;   // wrap: harmless re-stage of tile 0

        short8 af[4], bfr[4];

        // ================= phase 0: kk=0, m-half 0 =================
        stageA(tn, nxt);                                   // +4 in flight
        asm volatile("s_waitcnt vmcnt(4)" ::: "memory");   // tile t fully landed
        __builtin_amdgcn_s_barrier();
        {
            const int colb = (kb * 8) * 2;                 // kk=0
#pragma unroll
            for (int n = 0; n < 4; ++n) {
                int row = wc * 64 + n * 16 + lr;
                bfr[n] = *(const short8*)(cur + ABYTES + row * 128 + (colb ^ ((row & 7) << 4)));
            }
#pragma unroll
            for (int m = 0; m < 4; ++m) {
                int row = wr * 128 + m * 16 + lr;
                af[m] = *(const short8*)(cur + row * 128 + (colb ^ ((row & 7) << 4)));
            }
        }
        asm volatile("s_waitcnt lgkmcnt(0)" ::: "memory");
        __builtin_amdgcn_sched_barrier(0);
        __builtin_amdgcn_s_setprio(1);
#pragma unroll
        for (int m = 0; m < 4; ++m)
#pragma unroll
            for (int n = 0; n < 4; ++n)
                acc[m][n] = __builtin_amdgcn_mfma_f32_16x16x32_bf16(af[m], bfr[n], acc[m][n], 0, 0, 0);
        __builtin_amdgcn_s_setprio(0);
        __builtin_amdgcn_s_barrier();

        // ================= phase 1: kk=0, m-half 1 (reuse bfr) =================
        stageB(tn, nxt);
        {
            const int colb = (kb * 8) * 2;
#pragma unroll
            for (int m = 0; m < 4; ++m) {
                int row = wr * 128 + 64 + m * 16 + lr;
                af[m] = *(const short8*)(cur + row * 128 + (colb ^ ((row & 7) << 4)));
            }
        }
        asm volatile("s_waitcnt lgkmcnt(0)" ::: "memory");
        __builtin_amdgcn_sched_barrier(0);
        __builtin_amdgcn_s_setprio(1);
#pragma unroll
        for (int m = 0; m < 4; ++m)
#pragma unroll
            for (int n = 0; n < 4; ++n)
                acc[4 + m][n] = __builtin_amdgcn_mfma_f32_16x16x32_bf16(af[m], bfr[n], acc[4 + m][n], 0, 0, 0);
        __builtin_amdgcn_s_setprio(0);
        __builtin_amdgcn_s_barrier();

        // ================= phase 2: kk=1, m-half 0 =================
        {
            const int colb = (32 + kb * 8) * 2;            // kk=1
#pragma unroll
            for (int n = 0; n < 4; ++n) {
                int row = wc * 64 + n * 16 + lr;
                bfr[n] = *(const short8*)(cur + ABYTES + row * 128 + (colb ^ ((row & 7) << 4)));
            }
#pragma unroll
            for (int m = 0; m < 4; ++m) {
                int row = wr * 128 + m * 16 + lr;
                af[m] = *(const short8*)(cur + row * 128 + (colb ^ ((row & 7) << 4)));
            }
        }
        asm volatile("s_waitcnt lgkmcnt(0)" ::: "memory");
        __builtin_amdgcn_sched_barrier(0);
        __builtin_amdgcn_s_setprio(1);
#pragma unroll
        for (int m = 0; m < 4; ++m)
#pragma unroll
            for (int n = 0; n < 4; ++n)
                acc[m][n] = __builtin_amdgcn_mfma_f32_16x16x32_bf16(af[m], bfr[n], acc[m][n], 0, 0, 0);
        __builtin_amdgcn_s_setprio(0);
        __builtin_amdgcn_s_barrier();

        // ================= phase 3: kk=1, m-half 1 (reuse bfr) =================
        {
            const int colb = (32 + kb * 8) * 2;
#pragma unroll
            for (int m = 0; m < 4; ++m) {
                int row = wr * 128 + 64 + m * 16 + lr;
                af[m] = *(const short8*)(cur + row * 128 + (colb ^ ((row & 7) << 4)));
            }
        }
        asm volatile("s_waitcnt lgkmcnt(0)" ::: "memory");
        __builtin_amdgcn_sched_barrier(0);
        __builtin_amdgcn_s_setprio(1);
#pragma unroll
        for (int m = 0; m < 4; ++m)
#pragma unroll
            for (int n = 0; n < 4; ++n)
                acc[4 + m][n] = __builtin_amdgcn_mfma_f32_16x16x32_bf16(af[m], bfr[n], acc[4 + m][n], 0, 0, 0);
        __builtin_amdgcn_s_setprio(0);
        __builtin_amdgcn_s_barrier();
    }

    // epilogue: out = acc * scale + bias
    const float sc = scale[0];
    const int orow0 = brow + wr * 128;
    const int ocol0 = bcol + wc * 64;
    float bv[4];
#pragma unroll
    for (int n = 0; n < 4; ++n) bv[n] = bias[ocol0 + n * 16 + lr];
#pragma unroll
    for (int m = 0; m < 8; ++m) {
#pragma unroll
        for (int i = 0; i < 4; ++i) {
            int r = orow0 + m * 16 + kb * 4 + i;   // C/D: row=(lane>>4)*4+reg, col=lane&15
            size_t base = (size_t)r * N_TOT + ocol0;
#pragma unroll
            for (int n = 0; n < 4; ++n)
                out[base + n * 16 + lr] = acc[m][n][i] * sc + bv[n];
        }
    }
}

// ---------------- fallback (round-1 fused kernel) if ws too small ----------------
__device__ __forceinline__ unsigned long long pack4(float a, float b, float c, float d) {
    return (unsigned long long)f2bf(a)
         | ((unsigned long long)f2bf(b) << 16)
         | ((unsigned long long)f2bf(c) << 32)
         | ((unsigned long long)f2bf(d) << 48);
}

#define FBM 128
#define FBN 128

__global__ __launch_bounds__(256, 2)
void otf_linear_fused(const float* __restrict__ X, const int* __restrict__ W,
                      const float* __restrict__ scale, const float* __restrict__ bias,
                      float* __restrict__ out) {
    __shared__ __align__(16) unsigned char AsB[FBM * BK * 2];
    __shared__ __align__(16) unsigned char BsB[FBN * BK * 2];

    const int tid = threadIdx.x, lane = tid & 63, wid = tid >> 6;
    const int wr = wid >> 1, wc = wid & 1, lr = lane & 15, kb = lane >> 4;
    const int brow = blockIdx.y * FBM, bcol = blockIdx.x * FBN;
    const int srow = tid >> 4, sc4 = tid & 15;

    f32x4 areg[8];
    int4 breg[8];
    auto load_tiles = [&](int t) {
        const int k0 = t * BK;
#pragma unroll
        for (int p = 0; p < 8; ++p) {
            int row = p * 16 + srow;
            areg[p] = *(const f32x4*)(&X[(size_t)(brow + row) * K_TOT + k0 + sc4 * 4]);
            breg[p] = *(const int4*)(&W[(size_t)(bcol + row) * K_TOT + k0 + sc4 * 4]);
        }
    };
    auto store_tiles = [&]() {
#pragma unroll
        for (int p = 0; p < 8; ++p) {
            int row = p * 16 + srow;
            int boff = (sc4 * 8) ^ ((row & 7) << 4);
            *(unsigned long long*)(&AsB[row * 128 + boff]) =
                pack4(areg[p][0], areg[p][1], areg[p][2], areg[p][3]);
            *(unsigned long long*)(&BsB[row * 128 + boff]) =
                pack4((float)breg[p].x, (float)breg[p].y, (float)breg[p].z, (float)breg[p].w);
        }
    };

    f32x4 acc[4][4];
#pragma unroll
    for (int m = 0; m < 4; ++m)
#pragma unroll
        for (int n = 0; n < 4; ++n)
#pragma unroll
            for (int i = 0; i < 4; ++i) acc[m][n][i] = 0.0f;

    load_tiles(0);
    for (int t = 0; t < NT; ++t) {
        store_tiles();
        __syncthreads();
        if (t + 1 < NT) load_tiles(t + 1);
#pragma unroll
        for (int kk = 0; kk < 2; ++kk) {
            short8 af[4], bfr[4];
#pragma unroll
            for (int m = 0; m < 4; ++m) {
                int row = wr * 64 + m * 16 + lr;
                int col = (kk * 64 + kb * 16) ^ ((row & 7) << 4);
                af[m] = *(const short8*)(&AsB[row * 128 + col]);
            }
#pragma unroll
            for (int n = 0; n < 4; ++n) {
                int row = wc * 64 + n * 16 + lr;
                int col = (kk * 64 + kb * 16) ^ ((row & 7) << 4);
                bfr[n] = *(const short8*)(&BsB[row * 128 + col]);
            }
#pragma unroll
            for (int m = 0; m < 4; ++m)
#pragma unroll
                for (int n = 0; n < 4; ++n)
                    acc[m][n] = __builtin_amdgcn_mfma_f32_16x16x32_bf16(af[m], bfr[n], acc[m][n], 0, 0, 0);
        }
        __syncthreads();
    }

    const float sc = scale[0];
    const int orow0 = brow + wr * 64, ocol0 = bcol + wc * 64;
    float bv[4];
#pragma unroll
    for (int n = 0; n < 4; ++n) bv[n] = bias[ocol0 + n * 16 + lr];
#pragma unroll
    for (int m = 0; m < 4; ++m)
#pragma unroll
        for (int i = 0; i < 4; ++i) {
            int r = orow0 + m * 16 + kb * 4 + i;
            size_t base = (size_t)r * N_TOT + ocol0;
#pragma unroll
            for (int n = 0; n < 4; ++n)
                out[base + n * 16 + lr] = acc[m][n][i] * sc + bv[n];
        }
}

extern "C" void kernel_launch(void* const* d_in, const int* in_sizes, int n_in,
                              void* d_out, int out_size, void* d_ws, size_t ws_size,
                              hipStream_t stream) {
    const float* x     = (const float*)d_in[0];
    const int*   w     = (const int*)d_in[1];
    const float* scale = (const float*)d_in[2];
    const float* bias  = (const float*)d_in[3];
    float* out = (float*)d_out;

    const size_t W_ELEMS = (size_t)N_TOT * K_TOT;   // 45,088,768
    const size_t X_ELEMS = (size_t)M_TOT * K_TOT;   //  4,194,304
    const size_t need = (W_ELEMS + X_ELEMS) * sizeof(__hip_bfloat16);  // ~94 MB

    if (ws_size >= need) {
        __hip_bfloat16* Wb = (__hip_bfloat16*)d_ws;
        __hip_bfloat16* Xb = (__hip_bfloat16*)((char*)d_ws + W_ELEMS * 2);
        conv_kernel<<<2048, 256, 0, stream>>>(w, x, Wb, Xb,
                                              (int)(W_ELEMS / 8), (int)(X_ELEMS / 8));
        gemm_bf16_kernel<<<dim3(N_TOT / BN, M_TOT / BM), 512, 0, stream>>>(Xb, Wb, scale, bias, out);
    } else {
        otf_linear_fused<<<dim3(N_TOT / FBN, M_TOT / FBM), 256, 0, stream>>>(x, w, scale, bias, out);
    }
}